// Round 1
// baseline (36996.262 us; speedup 1.0000x reference)
//
#include <hip/hip_runtime.h>
#include <hip/hip_fp16.h>

// Problem constants
#define NN   514      // N = NUM_CLASSES + NUM_REPLABELS + 1
#define BB   32
#define TT   2000
#define LT   101      // 2*Lt+1
#define LTT  50
#define NSL  9        // slices per batch
#define RS   58       // rows per slice (9*58=522 >= 514)
#define RSTR 536      // LDS row stride (halves); 536*2/4 % 32 = 12 -> 2-way max
#define NEGV -1e30f

// workspace byte offsets
#define OFF_FLAG 0          // int   flags[32][9]          (1152 B)
#define OFF_MX   1280       // float MX[2][32][9]          (2304 B)
#define OFF_P    4096       // float PB[2][32][9][64]      (147456 B)
#define OFF_FCCP 153600     // float FCCP[32][9]           (1152 B)
#define OFF_FAL  155648     // float FAL[32]               (128 B)

typedef _Float16 h2t __attribute__((ext_vector_type(2)));

#if defined(__has_builtin)
#if __has_builtin(__builtin_amdgcn_fdot2)
#define HAVE_FDOT2 1
#endif
#endif
#ifndef HAVE_FDOT2
#define HAVE_FDOT2 0
#endif

__device__ __forceinline__ float dot2acc(unsigned a, unsigned b, float c) {
#if HAVE_FDOT2
  return __builtin_amdgcn_fdot2(__builtin_bit_cast(h2t, a),
                                __builtin_bit_cast(h2t, b), c, false);
#else
  h2t ha = __builtin_bit_cast(h2t, a), hb = __builtin_bit_cast(h2t, b);
  c += (float)ha[0] * (float)hb[0];
  c += (float)ha[1] * (float)hb[1];
  return c;
#endif
}

__global__ void k_reset(int* flags) {
  int i = threadIdx.x;
  if (i < BB * NSL) flags[i] = -1;
}

__global__ __launch_bounds__(256) void k_main(const float* __restrict__ inp,
                                              const float* __restrict__ tr,
                                              const int* __restrict__ tg,
                                              char* __restrict__ ws) {
  int*   flags = (int*)(ws + OFF_FLAG);
  float* MX    = (float*)(ws + OFF_MX);
  float* PB    = (float*)(ws + OFF_P);
  float* FCCP  = (float*)(ws + OFF_FCCP);
  float* FALV  = (float*)(ws + OFF_FAL);

  __shared__ __align__(16) __half expw[RS * RSTR];   // 62176 B
  __shared__ __align__(16) __half pall[4][144];      // 1152 B
  __shared__ float marr[16];
  __shared__ float red[8];
  __shared__ float betl[104];

  const int bid = blockIdx.x;
  const int tid = threadIdx.x;

  if (bid < NSL * BB) {
    // ================= FCC slice workgroup =================
    const int s  = bid >> 5;       // slice
    const int b  = bid & 31;       // batch
    const int r0 = s * RS;
    const int nr = (NN - r0 < RS) ? (NN - r0) : RS;

    // load exp(transmat) slice into LDS as fp16, zero-padded
    for (int u = tid; u < RS * RSTR; u += 256) {
      int i = u / RSTR, j = u - i * RSTR;
      float v = 0.f;
      if (i < nr && j < NN) v = __expf(tr[(size_t)(1 + r0 + i) * NN + j]);
      expw[u] = __float2half(v);
    }
    for (int u = tid; u < 4 * 144; u += 256) ((__half*)pall)[u] = __float2half(0.f);
    __syncthreads();

    const int  row    = tid >> 2;
    const int  q      = tid & 3;
    const bool rowOK  = (row < nr);
    const int  cstart = q << 7;                 // q*128
    const int  iters  = (q == 3) ? 17 : 16;     // *8 halves

    // ---- t = 0 ----
    float alpha = NEGV;
    if (rowOK && q == 0)
      alpha = inp[(size_t)b * TT * NN + (r0 + row)] + tr[r0 + row];

    float m_new, pval = 0.f;
    {
      float v = (rowOK && q == 0) ? alpha : NEGV;
      for (int mm = 1; mm < 64; mm <<= 1) v = fmaxf(v, __shfl_xor(v, mm));
      if ((tid & 63) == 0) red[tid >> 6] = v;
      __syncthreads();
      m_new = fmaxf(fmaxf(red[0], red[1]), fmaxf(red[2], red[3]));
      __syncthreads();
    }
    if (rowOK && q == 0) pval = __expf(alpha - m_new);
    {
      int par = 0;
      float* dst = PB + (((size_t)par * BB + b) * NSL + s) * 64;
      if (q == 0 && rowOK)
        __hip_atomic_store(&dst[row], pval, __ATOMIC_RELAXED, __HIP_MEMORY_SCOPE_AGENT);
      if (tid == 0)
        __hip_atomic_store(&MX[(par * BB + b) * NSL + s], m_new, __ATOMIC_RELAXED, __HIP_MEMORY_SCOPE_AGENT);
      __builtin_amdgcn_fence(__ATOMIC_RELEASE, "agent");
      __syncthreads();
      if (tid == 0)
        __hip_atomic_store(&flags[b * NSL + s], 0, __ATOMIC_RELAXED, __HIP_MEMORY_SCOPE_AGENT);
    }

    // preload e for t=1
    float e_reg = 0.f;
    if (rowOK && q == 0)
      e_reg = inp[(size_t)b * TT * NN + (size_t)1 * NN + r0 + row];

    for (int t = 1; t < TT; ++t) {
      // prefetch next e (hides HBM latency under this step)
      float e_nxt = 0.f;
      if (rowOK && q == 0) {
        int tn = (t + 1 < TT) ? (t + 1) : (TT - 1);
        e_nxt = inp[(size_t)b * TT * NN + (size_t)tn * NN + r0 + row];
      }

      const int tw  = t - 1;
      const int par = tw & 1;

      // spin for all 9 producer flags of step t-1
      if (tid < NSL) {
        int guard = 0;
        while (__hip_atomic_load(&flags[b * NSL + tid], __ATOMIC_RELAXED,
                                 __HIP_MEMORY_SCOPE_AGENT) < tw) {
          __builtin_amdgcn_s_sleep(1);
          if (++guard > (1 << 24)) break;   // anti-hang: fail visibly instead
        }
      }
      __builtin_amdgcn_fence(__ATOMIC_ACQUIRE, "agent");
      __syncthreads();

      // slice maxes
      if (tid < NSL)
        marr[tid] = __hip_atomic_load(&MX[(par * BB + b) * NSL + tid],
                                      __ATOMIC_RELAXED, __HIP_MEMORY_SCOPE_AGENT);
      __syncthreads();
      float M = marr[0];
      #pragma unroll
      for (int k = 1; k < NSL; ++k) M = fmaxf(M, marr[k]);

      // gather p, rescale per slice, pack fp16 into pall
      for (int u = tid; u < NSL * RS; u += 256) {
        if (u < NN) {
          int sp = u / RS;
          float pv = __hip_atomic_load(
              &PB[(((size_t)par * BB + b) * NSL + sp) * 64 + (u - sp * RS)],
              __ATOMIC_RELAXED, __HIP_MEMORY_SCOPE_AGENT);
          float sv = pv * __expf(marr[sp] - M);
          int qd = u >> 7; if (qd > 3) qd = 3;
          pall[qd][u - (qd << 7)] = __float2half(sv);
        }
      }
      __syncthreads();

      // matvec: d[row] = sum_j expw[row][j] * pall[j]
      float d = 0.f;
      if (rowOK) {
        const uint4* mp = (const uint4*)(expw + row * RSTR + cstart);
        const uint4* pp = (const uint4*)(&pall[q][0]);
        for (int k = 0; k < iters; ++k) {
          uint4 mm = mp[k];
          uint4 pv = pp[k];
          d = dot2acc(mm.x, pv.x, d);
          d = dot2acc(mm.y, pv.y, d);
          d = dot2acc(mm.z, pv.z, d);
          d = dot2acc(mm.w, pv.w, d);
        }
      }
      // reduce the 4 column-chunks of each row (lanes row*4+q are contiguous)
      d += __shfl_xor(d, 1);
      d += __shfl_xor(d, 2);

      float alpha_new = NEGV;
      if (rowOK && q == 0) alpha_new = e_reg + M + __logf(d);

      // slice max
      {
        float v = (rowOK && q == 0) ? alpha_new : NEGV;
        for (int mm = 1; mm < 64; mm <<= 1) v = fmaxf(v, __shfl_xor(v, mm));
        if ((tid & 63) == 0) red[tid >> 6] = v;
        __syncthreads();
        m_new = fmaxf(fmaxf(red[0], red[1]), fmaxf(red[2], red[3]));
        __syncthreads();
      }
      pval = (rowOK && q == 0) ? __expf(alpha_new - m_new) : 0.f;

      // publish
      {
        int pw = t & 1;
        float* dst = PB + (((size_t)pw * BB + b) * NSL + s) * 64;
        if (q == 0 && rowOK)
          __hip_atomic_store(&dst[row], pval, __ATOMIC_RELAXED, __HIP_MEMORY_SCOPE_AGENT);
        if (tid == 0)
          __hip_atomic_store(&MX[(pw * BB + b) * NSL + s], m_new, __ATOMIC_RELAXED, __HIP_MEMORY_SCOPE_AGENT);
        __builtin_amdgcn_fence(__ATOMIC_RELEASE, "agent");
        __syncthreads();
        if (tid == 0)
          __hip_atomic_store(&flags[b * NSL + s], t, __ATOMIC_RELAXED, __HIP_MEMORY_SCOPE_AGENT);
      }
      e_reg = e_nxt;
    }

    // final slice LSE -> FCCP[b][s]
    {
      float v = (rowOK && q == 0) ? pval : 0.f;
      for (int mm = 1; mm < 64; mm <<= 1) v += __shfl_xor(v, mm);
      if ((tid & 63) == 0) red[tid >> 6] = v;
      __syncthreads();
      float psum = red[0] + red[1] + red[2] + red[3];
      if (tid == 0) FCCP[b * NSL + s] = m_new + __logf(psum);
    }
  } else {
    // ================= FAL workgroup (one per batch) =================
    const int b = bid - NSL * BB;
    const int l = tid;
    int   tgtl = 0;
    float self_w = 0.f, move_w = NEGV;
    if (l < LT) {
      tgtl = (l & 1) ? (tg[b * LTT + (l >> 1)] + 1) : (NN - 1);
      self_w = tr[(size_t)(1 + tgtl) * NN + tgtl];
      if (l > 0) {
        int tgtm = ((l - 1) & 1) ? (tg[b * LTT + ((l - 1) >> 1)] + 1) : (NN - 1);
        move_w = tr[(size_t)(1 + tgtl) * NN + tgtm];
      }
    }
    float beta = NEGV;
    if (l == 0) beta = inp[(size_t)b * TT * NN + (NN - 1)] + tr[NN - 1];
    if (l < LT) betl[l] = beta;
    __syncthreads();

    float em_nxt = 0.f;
    if (l < LT) em_nxt = inp[(size_t)b * TT * NN + (size_t)1 * NN + tgtl];

    for (int t = 1; t < TT; ++t) {
      float em = em_nxt;
      if (l < LT) {
        int tn = (t + 1 < TT) ? (t + 1) : (TT - 1);
        em_nxt = inp[(size_t)b * TT * NN + (size_t)tn * NN + tgtl];
      }
      float bprev = (l > 0 && l < LT) ? betl[l - 1] : NEGV;
      float v1 = beta + self_w;
      float v2 = bprev + move_w;
      float mx = fmaxf(v1, v2), mn = fminf(v1, v2);
      float nb = em + mx + __logf(1.f + __expf(mn - mx));
      __syncthreads();
      if (l < LT) betl[l] = nb;
      beta = nb;
      __syncthreads();
    }
    if (l == LT - 1) FALV[b] = beta;
  }
}

__global__ void k_fin(const char* __restrict__ ws, float* __restrict__ out) {
  const float* FCCP = (const float*)(ws + OFF_FCCP);
  const float* FALV = (const float*)(ws + OFF_FAL);
  int tid = threadIdx.x;
  float v = 0.f;
  if (tid < BB) {
    float m = FCCP[tid * NSL];
    #pragma unroll
    for (int s = 1; s < NSL; ++s) m = fmaxf(m, FCCP[tid * NSL + s]);
    float sum = 0.f;
    #pragma unroll
    for (int s = 0; s < NSL; ++s) sum += __expf(FCCP[tid * NSL + s] - m);
    float fcc = m + __logf(sum);
    v = (fcc - FALV[tid]) * (1.0f / (float)LT);
  }
  for (int mm = 1; mm < 64; mm <<= 1) v += __shfl_xor(v, mm);
  if (tid == 0) out[0] = v / (float)BB;
}

extern "C" void kernel_launch(void* const* d_in, const int* in_sizes, int n_in,
                              void* d_out, int out_size, void* d_ws, size_t ws_size,
                              hipStream_t stream) {
  const float* inp = (const float*)d_in[0];
  const float* tr  = (const float*)d_in[1];
  const int*   tg  = (const int*)d_in[2];
  float* out = (float*)d_out;
  char*  ws  = (char*)d_ws;

  k_reset<<<dim3(1), dim3(512), 0, stream>>>((int*)(ws + OFF_FLAG));
  k_main<<<dim3(NSL * BB + BB), dim3(256), 0, stream>>>(inp, tr, tg, ws);
  k_fin<<<dim3(1), dim3(64), 0, stream>>>(ws, out);
}

// Round 2
// 7850.170 us; speedup vs baseline: 4.7128x; 4.7128x over previous
//
#include <hip/hip_runtime.h>
#include <hip/hip_fp16.h>

// Problem constants
#define NN   514      // N = NUM_CLASSES + NUM_REPLABELS + 1
#define BB   32
#define TT   2000
#define LT   101      // 2*Lt+1
#define LTT  50
#define NSL  9        // slices per batch
#define RS   58       // rows per slice (9*58=522 >= 514)
#define RSTR 536      // LDS row stride (halves)
#define NDW  261      // 9*29 packed dwords of p per batch-step
#define NEGV -1e30f

// workspace byte offsets
#define OFF_FLAG 0          // int   flags[32][9]           (1152 B)
#define OFF_MX   1280       // float MX[2][32][9]           (2304 B)
#define OFF_P    4096       // uint  PB16[2][32][9][32]     (73728 B)
#define OFF_FCCP 80000      // float FCCP[32][9]            (1152 B)
#define OFF_FAL  82048      // float FAL[32]                (128 B)

typedef _Float16 h2t __attribute__((ext_vector_type(2)));

#if defined(__has_builtin)
#if __has_builtin(__builtin_amdgcn_fdot2)
#define HAVE_FDOT2 1
#endif
#endif
#ifndef HAVE_FDOT2
#define HAVE_FDOT2 0
#endif

__device__ __forceinline__ float dot2acc(unsigned a, unsigned b, float c) {
#if HAVE_FDOT2
  return __builtin_amdgcn_fdot2(__builtin_bit_cast(h2t, a),
                                __builtin_bit_cast(h2t, b), c, false);
#else
  h2t ha = __builtin_bit_cast(h2t, a), hb = __builtin_bit_cast(h2t, b);
  c += (float)ha[0] * (float)hb[0];
  c += (float)ha[1] * (float)hb[1];
  return c;
#endif
}

__global__ void k_reset(int* flags) {
  int i = threadIdx.x;
  if (i < BB * NSL) flags[i] = -1;
}

__global__ __launch_bounds__(256) void k_main(const float* __restrict__ inp,
                                              const float* __restrict__ tr,
                                              const int* __restrict__ tg,
                                              char* __restrict__ ws) {
  int*      flags = (int*)(ws + OFF_FLAG);
  float*    MX    = (float*)(ws + OFF_MX);
  unsigned* PB16  = (unsigned*)(ws + OFF_P);
  float*    FCCP  = (float*)(ws + OFF_FCCP);
  float*    FALV  = (float*)(ws + OFF_FAL);

  __shared__ __align__(16) __half expw[RS * RSTR];   // 62176 B
  __shared__ __align__(16) __half pall[4][144];      // 1152 B
  __shared__ float marr[16];
  __shared__ float red[8];
  __shared__ float betl[104];

  const int bid = blockIdx.x;
  const int tid = threadIdx.x;

  if (bid < NSL * BB) {
    // ================= FCC slice workgroup =================
    const int s  = bid >> 5;       // slice
    const int b  = bid & 31;       // batch
    const int r0 = s * RS;
    const int nr = (NN - r0 < RS) ? (NN - r0) : RS;

    // load exp(transmat) slice into LDS as fp16, zero-padded
    for (int u = tid; u < RS * RSTR; u += 256) {
      int i = u / RSTR, j = u - i * RSTR;
      float v = 0.f;
      if (i < nr && j < NN) v = __expf(tr[(size_t)(1 + r0 + i) * NN + j]);
      expw[u] = __float2half(v);
    }
    for (int u = tid; u < 4 * 144; u += 256) ((__half*)pall)[u] = __float2half(0.f);
    __syncthreads();

    const int  row    = tid >> 2;
    const int  q      = tid & 3;
    const bool rowOK  = (row < nr);
    const int  cstart = q << 7;                 // q*128
    const int  iters  = (q == 3) ? 17 : 16;     // *8 halves

    // ---- t = 0 ----
    float alpha = NEGV;
    if (rowOK && q == 0)
      alpha = inp[(size_t)b * TT * NN + (r0 + row)] + tr[r0 + row];

    float m_new, pval = 0.f;
    {
      float v = (rowOK && q == 0) ? alpha : NEGV;
      for (int mm = 1; mm < 64; mm <<= 1) v = fmaxf(v, __shfl_xor(v, mm));
      if ((tid & 63) == 0) red[tid >> 6] = v;
      __syncthreads();
      m_new = fmaxf(fmaxf(red[0], red[1]), fmaxf(red[2], red[3]));
      __syncthreads();
    }
    if (rowOK && q == 0) pval = __expf(alpha - m_new);

    // publish t=0 (pack pairs of rows into one dword of 2 halves)
    {
      float phi = __shfl_down(pval, 4);
      if ((tid & 7) == 0 && rowOK) {
        __half2 hp;
        hp.x = __float2half(pval);
        hp.y = __float2half(phi);
        __hip_atomic_store(&PB16[(((size_t)0 * BB + b) * NSL + s) * 32 + (row >> 1)],
                           __builtin_bit_cast(unsigned, hp),
                           __ATOMIC_RELAXED, __HIP_MEMORY_SCOPE_AGENT);
      }
      if (tid == 0)
        __hip_atomic_store(&MX[(0 * BB + b) * NSL + s], m_new, __ATOMIC_RELAXED, __HIP_MEMORY_SCOPE_AGENT);
      asm volatile("s_waitcnt vmcnt(0)" ::: "memory");
      __syncthreads();
      if (tid == 0)
        __hip_atomic_store(&flags[b * NSL + s], 0, __ATOMIC_RELAXED, __HIP_MEMORY_SCOPE_AGENT);
    }

    // preload e for t=1
    float e_reg = 0.f;
    if (rowOK && q == 0)
      e_reg = inp[(size_t)b * TT * NN + (size_t)1 * NN + r0 + row];

    for (int t = 1; t < TT; ++t) {
      // prefetch next e (hides HBM latency under this step)
      float e_nxt = 0.f;
      if (rowOK && q == 0) {
        int tn = (t + 1 < TT) ? (t + 1) : (TT - 1);
        e_nxt = inp[(size_t)b * TT * NN + (size_t)tn * NN + r0 + row];
      }

      const int tw  = t - 1;
      const int par = tw & 1;

      // spin for all 9 producer flags of step t-1
      if (tid < NSL) {
        int guard = 0;
        while (__hip_atomic_load(&flags[b * NSL + tid], __ATOMIC_RELAXED,
                                 __HIP_MEMORY_SCOPE_AGENT) < tw) {
          if (++guard > (1 << 23)) break;   // anti-hang: fail visibly instead
        }
      }
      __syncthreads();
      asm volatile("" ::: "memory");

      // slice maxes
      if (tid < NSL)
        marr[tid] = __hip_atomic_load(&MX[(par * BB + b) * NSL + tid],
                                      __ATOMIC_RELAXED, __HIP_MEMORY_SCOPE_AGENT);
      __syncthreads();
      float M = marr[0];
      #pragma unroll
      for (int k = 1; k < NSL; ++k) M = fmaxf(M, marr[k]);

      // gather packed p dwords, rescale per slice, place fp16 pairs into pall
      for (int u = tid; u < NDW; u += 256) {
        int sp = u / 29;
        int rp = u - sp * 29;
        int hb = sp * RS + rp * 2;       // half index in [0, 522)
        if (hb < NN) {
          unsigned w = __hip_atomic_load(
              &PB16[(((size_t)par * BB + b) * NSL + sp) * 32 + rp],
              __ATOMIC_RELAXED, __HIP_MEMORY_SCOPE_AGENT);
          __half2 v = __builtin_bit_cast(__half2, w);
          __half2 sc2 = __float2half2_rn(__expf(marr[sp] - M));
          __half2 r = __hmul2(v, sc2);
          int qd = hb >> 7; if (qd > 3) qd = 3;
          *reinterpret_cast<__half2*>(&pall[qd][hb - (qd << 7)]) = r;
        }
      }
      __syncthreads();

      // matvec: d[row] = sum_j expw[row][j] * pall[j]
      float d = 0.f;
      if (rowOK) {
        const uint4* mp = (const uint4*)(expw + row * RSTR + cstart);
        const uint4* pp = (const uint4*)(&pall[q][0]);
        for (int k = 0; k < iters; ++k) {
          uint4 mm = mp[k];
          uint4 pv = pp[k];
          d = dot2acc(mm.x, pv.x, d);
          d = dot2acc(mm.y, pv.y, d);
          d = dot2acc(mm.z, pv.z, d);
          d = dot2acc(mm.w, pv.w, d);
        }
      }
      // reduce the 4 column-chunks of each row (lanes row*4+q are contiguous)
      d += __shfl_xor(d, 1);
      d += __shfl_xor(d, 2);

      float alpha_new = NEGV;
      if (rowOK && q == 0) alpha_new = e_reg + M + __logf(d);

      // slice max
      {
        float v = (rowOK && q == 0) ? alpha_new : NEGV;
        for (int mm = 1; mm < 64; mm <<= 1) v = fmaxf(v, __shfl_xor(v, mm));
        if ((tid & 63) == 0) red[tid >> 6] = v;
        __syncthreads();
        m_new = fmaxf(fmaxf(red[0], red[1]), fmaxf(red[2], red[3]));
        __syncthreads();
      }
      pval = (rowOK && q == 0) ? __expf(alpha_new - m_new) : 0.f;

      // publish
      {
        const int pw = t & 1;
        float phi = __shfl_down(pval, 4);
        if ((tid & 7) == 0 && rowOK) {
          __half2 hp;
          hp.x = __float2half(pval);
          hp.y = __float2half(phi);
          __hip_atomic_store(&PB16[(((size_t)pw * BB + b) * NSL + s) * 32 + (row >> 1)],
                             __builtin_bit_cast(unsigned, hp),
                             __ATOMIC_RELAXED, __HIP_MEMORY_SCOPE_AGENT);
        }
        if (tid == 0)
          __hip_atomic_store(&MX[(pw * BB + b) * NSL + s], m_new, __ATOMIC_RELAXED, __HIP_MEMORY_SCOPE_AGENT);
        asm volatile("s_waitcnt vmcnt(0)" ::: "memory");
        __syncthreads();
        if (tid == 0)
          __hip_atomic_store(&flags[b * NSL + s], t, __ATOMIC_RELAXED, __HIP_MEMORY_SCOPE_AGENT);
      }
      e_reg = e_nxt;
    }

    // final slice LSE -> FCCP[b][s]
    {
      float v = (rowOK && q == 0) ? pval : 0.f;
      for (int mm = 1; mm < 64; mm <<= 1) v += __shfl_xor(v, mm);
      if ((tid & 63) == 0) red[tid >> 6] = v;
      __syncthreads();
      float psum = red[0] + red[1] + red[2] + red[3];
      if (tid == 0) FCCP[b * NSL + s] = m_new + __logf(psum);
    }
  } else {
    // ================= FAL workgroup (one per batch) =================
    const int b = bid - NSL * BB;
    const int l = tid;
    int   tgtl = 0;
    float self_w = 0.f, move_w = NEGV;
    if (l < LT) {
      tgtl = (l & 1) ? (tg[b * LTT + (l >> 1)] + 1) : (NN - 1);
      self_w = tr[(size_t)(1 + tgtl) * NN + tgtl];
      if (l > 0) {
        int tgtm = ((l - 1) & 1) ? (tg[b * LTT + ((l - 1) >> 1)] + 1) : (NN - 1);
        move_w = tr[(size_t)(1 + tgtl) * NN + tgtm];
      }
    }
    float beta = NEGV;
    if (l == 0) beta = inp[(size_t)b * TT * NN + (NN - 1)] + tr[NN - 1];
    if (l < LT) betl[l] = beta;
    __syncthreads();

    float em_nxt = 0.f;
    if (l < LT) em_nxt = inp[(size_t)b * TT * NN + (size_t)1 * NN + tgtl];

    for (int t = 1; t < TT; ++t) {
      float em = em_nxt;
      if (l < LT) {
        int tn = (t + 1 < TT) ? (t + 1) : (TT - 1);
        em_nxt = inp[(size_t)b * TT * NN + (size_t)tn * NN + tgtl];
      }
      float bprev = (l > 0 && l < LT) ? betl[l - 1] : NEGV;
      float v1 = beta + self_w;
      float v2 = bprev + move_w;
      float mx = fmaxf(v1, v2), mn = fminf(v1, v2);
      float nb = em + mx + __logf(1.f + __expf(mn - mx));
      __syncthreads();
      if (l < LT) betl[l] = nb;
      beta = nb;
      __syncthreads();
    }
    if (l == LT - 1) FALV[b] = beta;
  }
}

__global__ void k_fin(const char* __restrict__ ws, float* __restrict__ out) {
  const float* FCCP = (const float*)(ws + OFF_FCCP);
  const float* FALV = (const float*)(ws + OFF_FAL);
  int tid = threadIdx.x;
  float v = 0.f;
  if (tid < BB) {
    float m = FCCP[tid * NSL];
    #pragma unroll
    for (int s = 1; s < NSL; ++s) m = fmaxf(m, FCCP[tid * NSL + s]);
    float sum = 0.f;
    #pragma unroll
    for (int s = 0; s < NSL; ++s) sum += __expf(FCCP[tid * NSL + s] - m);
    float fcc = m + __logf(sum);
    v = (fcc - FALV[tid]) * (1.0f / (float)LT);
  }
  for (int mm = 1; mm < 64; mm <<= 1) v += __shfl_xor(v, mm);
  if (tid == 0) out[0] = v / (float)BB;
}

extern "C" void kernel_launch(void* const* d_in, const int* in_sizes, int n_in,
                              void* d_out, int out_size, void* d_ws, size_t ws_size,
                              hipStream_t stream) {
  const float* inp = (const float*)d_in[0];
  const float* tr  = (const float*)d_in[1];
  const int*   tg  = (const int*)d_in[2];
  float* out = (float*)d_out;
  char*  ws  = (char*)d_ws;

  k_reset<<<dim3(1), dim3(512), 0, stream>>>((int*)(ws + OFF_FLAG));
  k_main<<<dim3(NSL * BB + BB), dim3(256), 0, stream>>>(inp, tr, tg, ws);
  k_fin<<<dim3(1), dim3(64), 0, stream>>>(ws, out);
}

// Round 3
// 5644.553 us; speedup vs baseline: 6.5543x; 1.3908x over previous
//
#include <hip/hip_runtime.h>
#include <hip/hip_fp16.h>

// Problem constants
#define NN   514      // N = NUM_CLASSES + NUM_REPLABELS + 1
#define BB   32
#define TT   2000
#define LT   101      // 2*Lt+1
#define LTT  50
#define NSL  9        // slices per batch
#define RS   58       // rows per slice (9*58=522 >= 514)
#define RSTR 536      // LDS row stride (halves)
#define QW   20       // tagged qwords per slice (3 fp16 each)
#define NQ   (NSL*QW) // 180 qwords per batch-step
#define NEGV -1e30f

typedef unsigned long long ull;

// workspace byte offsets
#define OFF_P    0          // ull PBQ[2][32][9][20]  (92160 B)
#define OFF_FCCP 92672      // float FCCP[32][9]      (1152 B)
#define OFF_FAL  94208      // float FAL[32]          (128 B)

typedef _Float16 h2t __attribute__((ext_vector_type(2)));

#if defined(__has_builtin)
#if __has_builtin(__builtin_amdgcn_fdot2)
#define HAVE_FDOT2 1
#endif
#endif
#ifndef HAVE_FDOT2
#define HAVE_FDOT2 0
#endif

__device__ __forceinline__ float dot2acc(unsigned a, unsigned b, float c) {
#if HAVE_FDOT2
  return __builtin_amdgcn_fdot2(__builtin_bit_cast(h2t, a),
                                __builtin_bit_cast(h2t, b), c, false);
#else
  h2t ha = __builtin_bit_cast(h2t, a), hb = __builtin_bit_cast(h2t, b);
  c += (float)ha[0] * (float)hb[0];
  c += (float)ha[1] * (float)hb[1];
  return c;
#endif
}

__global__ void k_reset(ull* q) {
  int i = blockIdx.x * 256 + threadIdx.x;
  if (i < 2 * BB * NSL * QW) q[i] = 0xFFFF000000000000ull;  // tag 0xFFFF = invalid
}

__global__ __launch_bounds__(256) void k_main(const float* __restrict__ inp,
                                              const float* __restrict__ tr,
                                              const int* __restrict__ tg,
                                              char* __restrict__ ws) {
  ull*   PBQ  = (ull*)(ws + OFF_P);
  float* FCCP = (float*)(ws + OFF_FCCP);
  float* FALV = (float*)(ws + OFF_FAL);

  __shared__ __align__(16) __half expw[RS * RSTR];   // 62176 B
  __shared__ __align__(16) __half pall[4][144];      // 1152 B
  __shared__ unsigned short ptmp[64];                // own slice p (fp16 bits)
  __shared__ float mls[12];                          // per-slice running max (consumer view)
  __shared__ float red[8];
  __shared__ float betl[104];

  const int bid = blockIdx.x;
  const int tid = threadIdx.x;

  if (bid < NSL * BB) {
    // ================= FCC slice workgroup =================
    const int s  = bid >> 5;       // slice
    const int b  = bid & 31;       // batch
    const int r0 = s * RS;
    const int nr = (NN - r0 < RS) ? (NN - r0) : RS;

    // load exp(transmat) slice into LDS as fp16, zero-padded
    for (int u = tid; u < RS * RSTR; u += 256) {
      int i = u / RSTR, j = u - i * RSTR;
      float v = 0.f;
      if (i < nr && j < NN) v = __expf(tr[(size_t)(1 + r0 + i) * NN + j]);
      expw[u] = __float2half(v);
    }
    for (int u = tid; u < 4 * 144; u += 256) ((__half*)pall)[u] = __float2half(0.f);
    if (tid < 64) ptmp[tid] = 0;
    if (tid < 12) mls[tid] = 0.f;
    __syncthreads();

    const int  row    = tid >> 2;
    const int  q      = tid & 3;
    const bool rowOK  = (row < nr);
    const int  cstart = q << 7;                 // q*128
    const int  iters  = (q == 3) ? 17 : 16;     // *8 halves

    const int  sp_u  = tid / QW;                // slice this thread polls
    const int  idx_u = tid - sp_u * QW;         // qword index within slice
    const bool extq  = (tid < NQ) && (sp_u != s);
    const bool anyq  = (tid < NQ);

    float m_run = 0.f, dqf_reg = 0.f, pval = 0.f, m_fin = 0.f;

    // ---- t = 0 ----
    float alpha = NEGV;
    if (rowOK && q == 0)
      alpha = inp[(size_t)b * TT * NN + (r0 + row)] + tr[r0 + row];
    {
      float v = (rowOK && q == 0) ? alpha : NEGV;
      for (int mm = 1; mm < 64; mm <<= 1) v = fmaxf(v, __shfl_xor(v, mm));
      if ((tid & 63) == 0) red[tid >> 6] = v;
      __syncthreads();
      float m_true = fmaxf(fmaxf(red[0], red[1]), fmaxf(red[2], red[3]));
      __half dqh = __float2half(m_true - m_run);
      dqf_reg = __half2float(dqh);
      m_run += dqf_reg;
      pval = (rowOK && q == 0) ? __expf(alpha - m_run) : 0.f;
      if (rowOK && q == 0) ptmp[row] = __half_as_ushort(__float2half(pval));
      __syncthreads();
      if (tid < QW) {
        unsigned short h0 = ptmp[3 * tid];
        unsigned short h1 = (tid == QW - 1) ? __half_as_ushort(dqh) : ptmp[3 * tid + 1];
        unsigned short h2 = (tid == QW - 1) ? (unsigned short)0 : ptmp[3 * tid + 2];
        ull w = (ull)h0 | ((ull)h1 << 16) | ((ull)h2 << 32);  // tag 0 in high bits
        __hip_atomic_store(&PBQ[(((size_t)0 * BB + b) * NSL + s) * QW + tid], w,
                           __ATOMIC_RELAXED, __HIP_MEMORY_SCOPE_AGENT);
      }
    }

    // preload e for t=1
    float e_reg = 0.f;
    if (rowOK && q == 0)
      e_reg = inp[(size_t)b * TT * NN + (size_t)1 * NN + r0 + row];

    for (int t = 1; t < TT; ++t) {
      // prefetch next e
      float e_nxt = 0.f;
      if (rowOK && q == 0) {
        int tn = (t + 1 < TT) ? (t + 1) : (TT - 1);
        e_nxt = inp[(size_t)b * TT * NN + (size_t)tn * NN + r0 + row];
      }

      const unsigned want = (unsigned)((t - 1) & 0xffff);
      const int      par  = (t - 1) & 1;

      // poll own tagged qword of each external slice (tag IS the flag)
      ull vq = 0;
      if (extq) {
        const ull* src = PBQ + (((size_t)par * BB + b) * NSL + sp_u) * QW + idx_u;
        int guard = 0;
        do {
          vq = __hip_atomic_load(src, __ATOMIC_RELAXED, __HIP_MEMORY_SCOPE_AGENT);
        } while ((unsigned)(vq >> 48) != want && ++guard < (1 << 22));
      }
      __syncthreads();                                   // 1: all data present

      // per-slice running max update via fp16 deltas (identical on all WGs)
      if (anyq && idx_u == QW - 1) {
        float dqf = (sp_u == s) ? dqf_reg
                  : __half2float(__ushort_as_half((unsigned short)(vq >> 16)));
        mls[sp_u] += dqf;
      }
      __syncthreads();                                   // 2: mls ready

      float M = mls[0];
      #pragma unroll
      for (int k = 1; k < NSL; ++k) M = fmaxf(M, mls[k]);

      // scatter p into pall, rescaled to global max M
      if (anyq) {
        float scale = __expf(mls[sp_u] - M);
        #pragma unroll
        for (int e = 0; e < 3; ++e) {
          int jj = 3 * idx_u + e;
          if (jj < RS) {
            unsigned short hv = (sp_u == s) ? ptmp[jj]
                                            : (unsigned short)(vq >> (16 * e));
            float pv = __half2float(__ushort_as_half(hv)) * scale;
            int j = sp_u * RS + jj;
            int qd = j >> 7; if (qd > 3) qd = 3;
            pall[qd][j - (qd << 7)] = __float2half(pv);
          }
        }
      }
      __syncthreads();                                   // 3: pall ready

      // matvec: d[row] = sum_j expw[row][j] * pall[j]
      float d = 0.f;
      if (rowOK) {
        const uint4* mp = (const uint4*)(expw + row * RSTR + cstart);
        const uint4* pp = (const uint4*)(&pall[q][0]);
        for (int k = 0; k < iters; ++k) {
          uint4 mm = mp[k];
          uint4 pv = pp[k];
          d = dot2acc(mm.x, pv.x, d);
          d = dot2acc(mm.y, pv.y, d);
          d = dot2acc(mm.z, pv.z, d);
          d = dot2acc(mm.w, pv.w, d);
        }
      }
      d += __shfl_xor(d, 1);
      d += __shfl_xor(d, 2);

      float alpha_new = (rowOK && q == 0) ? (e_reg + M + __logf(d)) : NEGV;

      // slice max + delta + publish
      {
        float v = alpha_new;
        for (int mm = 1; mm < 64; mm <<= 1) v = fmaxf(v, __shfl_xor(v, mm));
        if ((tid & 63) == 0) red[tid >> 6] = v;
        __syncthreads();                                 // 4: red ready
        float m_true = fmaxf(fmaxf(red[0], red[1]), fmaxf(red[2], red[3]));
        __half dqh = __float2half(m_true - m_run);
        dqf_reg = __half2float(dqh);
        m_run += dqf_reg;
        pval = (rowOK && q == 0) ? __expf(alpha_new - m_run) : 0.f;
        if (rowOK && q == 0) ptmp[row] = __half_as_ushort(__float2half(pval));
        __syncthreads();                                 // 5: ptmp ready
        if (tid < QW) {
          unsigned short h0 = ptmp[3 * tid];
          unsigned short h1 = (tid == QW - 1) ? __half_as_ushort(dqh) : ptmp[3 * tid + 1];
          unsigned short h2 = (tid == QW - 1) ? (unsigned short)0 : ptmp[3 * tid + 2];
          ull w = (ull)h0 | ((ull)h1 << 16) | ((ull)h2 << 32) |
                  ((ull)(t & 0xffff) << 48);
          __hip_atomic_store(&PBQ[(((size_t)(t & 1) * BB + b) * NSL + s) * QW + tid], w,
                             __ATOMIC_RELAXED, __HIP_MEMORY_SCOPE_AGENT);
          // no vmcnt drain: the tag travels with the data
        }
      }
      m_fin = m_run;
      e_reg = e_nxt;
    }

    // final slice LSE -> FCCP[b][s]
    {
      __syncthreads();
      float v = (rowOK && q == 0) ? pval : 0.f;
      for (int mm = 1; mm < 64; mm <<= 1) v += __shfl_xor(v, mm);
      if ((tid & 63) == 0) red[tid >> 6] = v;
      __syncthreads();
      float psum = red[0] + red[1] + red[2] + red[3];
      if (tid == 0) FCCP[b * NSL + s] = m_fin + __logf(psum);
    }
  } else {
    // ================= FAL workgroup (one per batch) =================
    const int b = bid - NSL * BB;
    const int l = tid;
    int   tgtl = 0;
    float self_w = 0.f, move_w = NEGV;
    if (l < LT) {
      tgtl = (l & 1) ? (tg[b * LTT + (l >> 1)] + 1) : (NN - 1);
      self_w = tr[(size_t)(1 + tgtl) * NN + tgtl];
      if (l > 0) {
        int tgtm = ((l - 1) & 1) ? (tg[b * LTT + ((l - 1) >> 1)] + 1) : (NN - 1);
        move_w = tr[(size_t)(1 + tgtl) * NN + tgtm];
      }
    }
    float beta = NEGV;
    if (l == 0) beta = inp[(size_t)b * TT * NN + (NN - 1)] + tr[NN - 1];
    if (l < LT) betl[l] = beta;
    __syncthreads();

    float em_nxt = 0.f;
    if (l < LT) em_nxt = inp[(size_t)b * TT * NN + (size_t)1 * NN + tgtl];

    for (int t = 1; t < TT; ++t) {
      float em = em_nxt;
      if (l < LT) {
        int tn = (t + 1 < TT) ? (t + 1) : (TT - 1);
        em_nxt = inp[(size_t)b * TT * NN + (size_t)tn * NN + tgtl];
      }
      float bprev = (l > 0 && l < LT) ? betl[l - 1] : NEGV;
      float v1 = beta + self_w;
      float v2 = bprev + move_w;
      float mx = fmaxf(v1, v2), mn = fminf(v1, v2);
      float nb = em + mx + __logf(1.f + __expf(mn - mx));
      __syncthreads();
      if (l < LT) betl[l] = nb;
      beta = nb;
      __syncthreads();
    }
    if (l == LT - 1) FALV[b] = beta;
  }
}

__global__ void k_fin(const char* __restrict__ ws, float* __restrict__ out) {
  const float* FCCP = (const float*)(ws + OFF_FCCP);
  const float* FALV = (const float*)(ws + OFF_FAL);
  int tid = threadIdx.x;
  float v = 0.f;
  if (tid < BB) {
    float m = FCCP[tid * NSL];
    #pragma unroll
    for (int s = 1; s < NSL; ++s) m = fmaxf(m, FCCP[tid * NSL + s]);
    float sum = 0.f;
    #pragma unroll
    for (int s = 0; s < NSL; ++s) sum += __expf(FCCP[tid * NSL + s] - m);
    float fcc = m + __logf(sum);
    v = (fcc - FALV[tid]) * (1.0f / (float)LT);
  }
  for (int mm = 1; mm < 64; mm <<= 1) v += __shfl_xor(v, mm);
  if (tid == 0) out[0] = v / (float)BB;
}

extern "C" void kernel_launch(void* const* d_in, const int* in_sizes, int n_in,
                              void* d_out, int out_size, void* d_ws, size_t ws_size,
                              hipStream_t stream) {
  const float* inp = (const float*)d_in[0];
  const float* tr  = (const float*)d_in[1];
  const int*   tg  = (const int*)d_in[2];
  float* out = (float*)d_out;
  char*  ws  = (char*)d_ws;

  k_reset<<<dim3(45), dim3(256), 0, stream>>>((ull*)(ws + OFF_P));
  k_main<<<dim3(NSL * BB + BB), dim3(256), 0, stream>>>(inp, tr, tg, ws);
  k_fin<<<dim3(1), dim3(64), 0, stream>>>(ws, out);
}

// Round 4
// 4476.811 us; speedup vs baseline: 8.2640x; 1.2608x over previous
//
#include <hip/hip_runtime.h>
#include <hip/hip_fp16.h>

// Problem constants
#define NN   514      // N = NUM_CLASSES + NUM_REPLABELS + 1
#define BB   32
#define TT   2000
#define LT   101      // 2*Lt+1
#define LTT  50
#define NSL  9        // slices per batch
#define RS   58       // rows per slice (9*58=522 >= 514)
#define RSTR 536      // LDS row stride (halves)
#define QW   20       // tagged qwords per slice (3 fp16 each)
#define NQ   (NSL*QW) // 180 qwords per batch-step
#define NEGV -1e30f

typedef unsigned long long ull;

// workspace byte offsets
#define OFF_P    0          // ull PBQ[2][32][9][20]  (92160 B)
#define OFF_FCCP 92672      // float FCCP[32][9]      (1152 B)
#define OFF_FAL  94208      // float FAL[32]          (128 B)

typedef _Float16 h2t __attribute__((ext_vector_type(2)));

#if defined(__has_builtin)
#if __has_builtin(__builtin_amdgcn_fdot2)
#define HAVE_FDOT2 1
#endif
#endif
#ifndef HAVE_FDOT2
#define HAVE_FDOT2 0
#endif

__device__ __forceinline__ float dot2acc(unsigned a, unsigned b, float c) {
#if HAVE_FDOT2
  return __builtin_amdgcn_fdot2(__builtin_bit_cast(h2t, a),
                                __builtin_bit_cast(h2t, b), c, false);
#else
  h2t ha = __builtin_bit_cast(h2t, a), hb = __builtin_bit_cast(h2t, b);
  c += (float)ha[0] * (float)hb[0];
  c += (float)ha[1] * (float)hb[1];
  return c;
#endif
}

__global__ void k_reset(ull* q) {
  int i = blockIdx.x * 256 + threadIdx.x;
  if (i < 2 * BB * NSL * QW) q[i] = 0xFFFF000000000000ull;  // tag 0xFFFF = invalid
}

__global__ __launch_bounds__(256) void k_main(const float* __restrict__ inp,
                                              const float* __restrict__ tr,
                                              const int* __restrict__ tg,
                                              char* __restrict__ ws) {
  ull*   PBQ  = (ull*)(ws + OFF_P);
  float* FCCP = (float*)(ws + OFF_FCCP);
  float* FALV = (float*)(ws + OFF_FAL);

  __shared__ __align__(16) __half expw[RS * RSTR];   // 62176 B
  __shared__ __align__(16) __half pall[4][144];      // 1152 B
  __shared__ unsigned short ptmp[64];                // own slice p (fp16 bits), wave-0 private
  __shared__ float mls[12];                          // per-slice running max (absolute)
  __shared__ float dpart[4][64];                     // matvec partials (q-chunk x row)
  __shared__ float betl[104];

  const int bid = blockIdx.x;
  const int tid = threadIdx.x;

  if (bid < NSL * BB) {
    // ================= FCC slice workgroup =================
    const int s  = bid >> 5;       // slice
    const int b  = bid & 31;       // batch
    const int r0 = s * RS;
    const int nr = (NN - r0 < RS) ? (NN - r0) : RS;

    // load exp(transmat) slice into LDS as fp16, zero-padded
    for (int u = tid; u < RS * RSTR; u += 256) {
      int i = u / RSTR, j = u - i * RSTR;
      float v = 0.f;
      if (i < nr && j < NN) v = __expf(tr[(size_t)(1 + r0 + i) * NN + j]);
      expw[u] = __float2half(v);
    }
    for (int u = tid; u < 4 * 144; u += 256) ((__half*)pall)[u] = __float2half(0.f);
    if (tid < 12) mls[tid] = 0.f;
    __syncthreads();

    const int  row   = tid & 63;   // row within slice (wave-lane)
    const int  q     = tid >> 6;   // column quarter == wave id
    const bool w0    = (q == 0);
    const bool rowOK = (row < nr);
    const int  iters = (q == 3) ? 17 : 16;

    // pollers live in waves 1..3 (tid 64..243)
    const int  u     = tid - 64;
    const bool isP   = (u >= 0) && (u < NQ);
    const int  sp_u  = isP ? (u / QW) : 0;
    const int  idx_u = isP ? (u - sp_u * QW) : 0;
    const bool ext   = isP && (sp_u != s);
    float macc = 0.f;              // register-accumulated max of polled slice

    float m_run = 0.f, pval = 0.f;
    unsigned short dq_bits = 0;
    float e_reg = 0.f;

    // ---- t = 0 : wave 0 computes alpha0, publishes ----
    if (w0) {
      float alpha = rowOK ? (inp[(size_t)b * TT * NN + (r0 + row)] + tr[r0 + row])
                          : NEGV;
      float v = alpha;
      #pragma unroll
      for (int mm = 1; mm < 64; mm <<= 1) v = fmaxf(v, __shfl_xor(v, mm));
      __half dqh = __float2half(v - m_run);
      m_run += __half2float(dqh);
      dq_bits = __half_as_ushort(dqh);
      pval = rowOK ? __expf(alpha - m_run) : 0.f;
      ptmp[row] = rowOK ? __half_as_ushort(__float2half(pval)) : (unsigned short)0;
      // intra-wave LDS write->read: ordered by lgkmcnt, no barrier needed
      if (tid < QW) {
        unsigned short h0 = ptmp[3 * tid];
        unsigned short h1 = (tid == QW - 1) ? dq_bits : ptmp[3 * tid + 1];
        unsigned short h2 = (tid == QW - 1) ? (unsigned short)0 : ptmp[3 * tid + 2];
        ull w = (ull)h0 | ((ull)h1 << 16) | ((ull)h2 << 32);  // tag 0
        __hip_atomic_store(&PBQ[(((size_t)0 * BB + b) * NSL + s) * QW + tid], w,
                           __ATOMIC_RELAXED, __HIP_MEMORY_SCOPE_AGENT);
      }
      if (rowOK) e_reg = inp[(size_t)b * TT * NN + (size_t)1 * NN + r0 + row];
    }

    for (int t = 1; t < TT; ++t) {
      // prefetch next e (wave 0 only)
      float e_nxt = 0.f;
      if (w0 && rowOK) {
        int tn = (t + 1 < TT) ? (t + 1) : (TT - 1);
        e_nxt = inp[(size_t)b * TT * NN + (size_t)tn * NN + r0 + row];
      }

      const unsigned want = (unsigned)((t - 1) & 0xffff);
      const int      par  = (t - 1) & 1;

      // waves 1-3: poll tagged qwords (tag IS the flag)
      ull vq = 0;
      if (ext) {
        const ull* src = PBQ + (((size_t)par * BB + b) * NSL + sp_u) * QW + idx_u;
        int guard = 0;
        do {
          vq = __hip_atomic_load(src, __ATOMIC_RELAXED, __HIP_MEMORY_SCOPE_AGENT);
        } while ((unsigned)(vq >> 48) != want && ++guard < (1 << 22));
        if (idx_u == QW - 1) {
          macc += __half2float(__ushort_as_half((unsigned short)(vq >> 16)));
          mls[sp_u] = macc;
        }
      }
      if (tid == 0) mls[s] = m_run;   // own slice absolute max (wave 0 register)
      __syncthreads();                                 // A: mls + messages ready

      float M = mls[0];
      #pragma unroll
      for (int k = 1; k < NSL; ++k) M = fmaxf(M, mls[k]);

      // scatter p into pall, rescaled to global max M
      if (ext) {
        float scale = __expf(mls[sp_u] - M);
        #pragma unroll
        for (int e = 0; e < 3; ++e) {
          int jj = 3 * idx_u + e;
          if (jj < RS) {
            float pv = __half2float(__ushort_as_half((unsigned short)(vq >> (16 * e)))) * scale;
            int j = sp_u * RS + jj;
            int qd = j >> 7; if (qd > 3) qd = 3;
            pall[qd][j - (qd << 7)] = __float2half(pv);
          }
        }
      } else if (w0 && tid < QW) {       // own slice from ptmp (wave-0 private)
        float scale = __expf(m_run - M);
        #pragma unroll
        for (int e = 0; e < 3; ++e) {
          int jj = 3 * tid + e;
          if (jj < RS) {
            float pv = __half2float(__ushort_as_half(ptmp[jj])) * scale;
            int j = s * RS + jj;
            int qd = j >> 7; if (qd > 3) qd = 3;
            pall[qd][j - (qd << 7)] = __float2half(pv);
          }
        }
      }
      __syncthreads();                                 // B: pall ready

      // matvec: dpart[q][row] = sum_{j in q's quarter} expw[row][j] * pall[j]
      float d = 0.f;
      if (rowOK) {
        const uint4* mp = (const uint4*)(expw + row * RSTR + (q << 7));
        const uint4* pp = (const uint4*)(&pall[q][0]);
        for (int k = 0; k < iters; ++k) {
          uint4 mm = mp[k];
          uint4 pv = pp[k];
          d = dot2acc(mm.x, pv.x, d);
          d = dot2acc(mm.y, pv.y, d);
          d = dot2acc(mm.z, pv.z, d);
          d = dot2acc(mm.w, pv.w, d);
        }
      }
      dpart[q][row] = d;
      __syncthreads();                                 // C: dpart ready

      // wave 0: serial tail (sum, alpha, max, publish) — no barriers.
      // waves 1-3 fall through and start polling step t's messages immediately.
      if (w0) {
        float dsum = dpart[0][row] + dpart[1][row] + dpart[2][row] + dpart[3][row];
        float alpha_new = rowOK ? (e_reg + M + __logf(dsum)) : NEGV;
        float v = alpha_new;
        #pragma unroll
        for (int mm = 1; mm < 64; mm <<= 1) v = fmaxf(v, __shfl_xor(v, mm));
        __half dqh = __float2half(v - m_run);
        m_run += __half2float(dqh);
        dq_bits = __half_as_ushort(dqh);
        pval = rowOK ? __expf(alpha_new - m_run) : 0.f;
        ptmp[row] = rowOK ? __half_as_ushort(__float2half(pval)) : (unsigned short)0;
        if (tid < QW) {
          unsigned short h0 = ptmp[3 * tid];
          unsigned short h1 = (tid == QW - 1) ? dq_bits : ptmp[3 * tid + 1];
          unsigned short h2 = (tid == QW - 1) ? (unsigned short)0 : ptmp[3 * tid + 2];
          ull w = (ull)h0 | ((ull)h1 << 16) | ((ull)h2 << 32) |
                  ((ull)(t & 0xffff) << 48);
          __hip_atomic_store(&PBQ[(((size_t)(t & 1) * BB + b) * NSL + s) * QW + tid], w,
                             __ATOMIC_RELAXED, __HIP_MEMORY_SCOPE_AGENT);
        }
        e_reg = e_nxt;
      }
    }

    // final slice LSE -> FCCP[b][s] (wave 0 holds pval/m_run)
    if (w0) {
      float v = pval;
      #pragma unroll
      for (int mm = 1; mm < 64; mm <<= 1) v += __shfl_xor(v, mm);
      if (tid == 0) FCCP[b * NSL + s] = m_run + __logf(v);
    }
  } else {
    // ================= FAL workgroup (one per batch) =================
    const int b = bid - NSL * BB;
    const int l = tid;
    int   tgtl = 0;
    float self_w = 0.f, move_w = NEGV;
    if (l < LT) {
      tgtl = (l & 1) ? (tg[b * LTT + (l >> 1)] + 1) : (NN - 1);
      self_w = tr[(size_t)(1 + tgtl) * NN + tgtl];
      if (l > 0) {
        int tgtm = ((l - 1) & 1) ? (tg[b * LTT + ((l - 1) >> 1)] + 1) : (NN - 1);
        move_w = tr[(size_t)(1 + tgtl) * NN + tgtm];
      }
    }
    float beta = NEGV;
    if (l == 0) beta = inp[(size_t)b * TT * NN + (NN - 1)] + tr[NN - 1];
    if (l < LT) betl[l] = beta;
    __syncthreads();

    float em_nxt = 0.f;
    if (l < LT) em_nxt = inp[(size_t)b * TT * NN + (size_t)1 * NN + tgtl];

    for (int t = 1; t < TT; ++t) {
      float em = em_nxt;
      if (l < LT) {
        int tn = (t + 1 < TT) ? (t + 1) : (TT - 1);
        em_nxt = inp[(size_t)b * TT * NN + (size_t)tn * NN + tgtl];
      }
      float bprev = (l > 0 && l < LT) ? betl[l - 1] : NEGV;
      float v1 = beta + self_w;
      float v2 = bprev + move_w;
      float mx = fmaxf(v1, v2), mn = fminf(v1, v2);
      float nb = em + mx + __logf(1.f + __expf(mn - mx));
      __syncthreads();
      if (l < LT) betl[l] = nb;
      beta = nb;
      __syncthreads();
    }
    if (l == LT - 1) FALV[b] = beta;
  }
}

__global__ void k_fin(const char* __restrict__ ws, float* __restrict__ out) {
  const float* FCCP = (const float*)(ws + OFF_FCCP);
  const float* FALV = (const float*)(ws + OFF_FAL);
  int tid = threadIdx.x;
  float v = 0.f;
  if (tid < BB) {
    float m = FCCP[tid * NSL];
    #pragma unroll
    for (int s = 1; s < NSL; ++s) m = fmaxf(m, FCCP[tid * NSL + s]);
    float sum = 0.f;
    #pragma unroll
    for (int s = 0; s < NSL; ++s) sum += __expf(FCCP[tid * NSL + s] - m);
    float fcc = m + __logf(sum);
    v = (fcc - FALV[tid]) * (1.0f / (float)LT);
  }
  for (int mm = 1; mm < 64; mm <<= 1) v += __shfl_xor(v, mm);
  if (tid == 0) out[0] = v / (float)BB;
}

extern "C" void kernel_launch(void* const* d_in, const int* in_sizes, int n_in,
                              void* d_out, int out_size, void* d_ws, size_t ws_size,
                              hipStream_t stream) {
  const float* inp = (const float*)d_in[0];
  const float* tr  = (const float*)d_in[1];
  const int*   tg  = (const int*)d_in[2];
  float* out = (float*)d_out;
  char*  ws  = (char*)d_ws;

  k_reset<<<dim3(45), dim3(256), 0, stream>>>((ull*)(ws + OFF_P));
  k_main<<<dim3(NSL * BB + BB), dim3(256), 0, stream>>>(inp, tr, tg, ws);
  k_fin<<<dim3(1), dim3(64), 0, stream>>>(ws, out);
}